// Round 11
// baseline (20999.170 us; speedup 1.0000x reference)
//
#include <hip/hip_runtime.h>
#include <math.h>

// ---------------- problem constants ----------------
#define T_LEN 2048
#define NTH   512
// 128 blocks: group = bid&7 (8 groups x 16 batches, full MFMA-N), slice = bid>>3 (0..15)
// blocks of a group = bids {g, g+8, ...} -> same XCD under round-robin dispatch (perf only)
// 8 waves: w0-3 L0 tile (wid&3), w4-7 L1 tile. Per-wave finishers. FC on w0, rotating slice.

typedef __attribute__((ext_vector_type(8))) short short8v;  // 8 bf16
typedef __attribute__((ext_vector_type(4))) float f32x4;
typedef unsigned int u32t;
typedef unsigned long long u64t;

// ---------------- ws layout (u32 units) ----------------
// h element: fp32 bits of h (|h|<1 => bit30==0) | gen<<30, gen=(step>>2)&1.
// step s lives in slot s&3. Init = 0x40000000 (gen=1 => stale before first write).
#define H1_OFF  0            // [4 slots][8 grp][16 batch][256 hid] = 131072 u32
#define H2_OFF  131072
#define ABT_OFF 262144
#define WS_U32  262145       // ~1.05 MB

// ---------------- LDS ----------------
// staging[2 pp][4 planes (h1hi,h1lo,h2hi,h2lo)][16 rows][512 B], XOR-swizzled (16B chunks).
// 64 KB used; allocate 128 KB -> exactly 1 block/CU.

__device__ __forceinline__ float fsigm(float x) {
  return __builtin_amdgcn_rcpf(1.0f + __builtin_amdgcn_exp2f(-1.44269504f * x));
}
__device__ __forceinline__ float ftanh(float x) {
  return fmaf(-2.0f, __builtin_amdgcn_rcpf(1.0f + __builtin_amdgcn_exp2f(2.88539009f * x)), 1.0f);
}
__device__ __forceinline__ u32t bf_rn(float x) {
  u32t b; __builtin_memcpy(&b, &x, 4);
  return (b + 0x7FFFu + ((b >> 16) & 1u)) >> 16;
}
__device__ __forceinline__ void split_bf(float x, u32t& hi, u32t& lo) {
  hi = bf_rn(x);
  u32t hb = hi << 16; float hf; __builtin_memcpy(&hf, &hb, 4);
  lo = bf_rn(x - hf);
}

__global__ void init_ws_kernel(u32t* ws) {
  for (int i = blockIdx.x * blockDim.x + threadIdx.x; i < WS_U32;
       i += gridDim.x * blockDim.x)
    ws[i] = (i < ABT_OFF) ? 0x40000000u : 0u;
}

#define MFMA16(a, b, c) __builtin_amdgcn_mfma_f32_16x16x32_bf16(a, b, c, 0, 0, 0)
#define ALD64(ptr) __hip_atomic_load((ptr), __ATOMIC_RELAXED, __HIP_MEMORY_SCOPE_AGENT)
#define ALD32(ptr) __hip_atomic_load((ptr), __ATOMIC_RELAXED, __HIP_MEMORY_SCOPE_AGENT)
#define AST32(ptr, v) __hip_atomic_store((ptr), (v), __ATOMIC_RELAXED, __HIP_MEMORY_SCOPE_AGENT)

__launch_bounds__(NTH, 2)
__global__ void lstm_persist(const float* __restrict__ y,
                             const float* __restrict__ Wih0, const float* __restrict__ Whh0,
                             const float* __restrict__ bih0, const float* __restrict__ bhh0,
                             const float* __restrict__ Wih1, const float* __restrict__ Whh1,
                             const float* __restrict__ bih1, const float* __restrict__ bhh1,
                             const float* __restrict__ Wfc, const float* __restrict__ bfc,
                             float* __restrict__ out, u32t* wsu) {
  extern __shared__ char lds[];
  const int tid   = threadIdx.x;
  const int lane  = tid & 63;
  const int wid   = tid >> 6;
  const int group = blockIdx.x & 7;
  const int slice = blockIdx.x >> 3;

  u32t* h1b    = wsu + H1_OFF;
  u32t* h2b    = wsu + H2_OFF;
  u32t* abortf = wsu + ABT_OFF;

  // zero both staging buffers (initial h = 0)
  for (int i = tid; i < 16384; i += NTH) ((u32t*)lds)[i] = 0u;

  const bool isL1 = (wid >= 4);
  const int  m = lane & 15, kq4 = lane >> 4;
  const int  gate = m & 3, hs4 = m >> 2;           // A row m = hs4*4 + gate
  const int  hidb = slice * 16 + (wid & 3) * 4;
  const int  grow = gate * 256 + hidb + hs4;

  // ---- A-fragment preload (split hi/lo bf16), full K per wave ----
  const float* WA = isL1 ? Wih1 : Whh0;
  const float* WB = isL1 ? Whh1 : Wfc;
  const int   rowB   = isL1 ? grow : m;
  const bool  bValid = isL1 || (wid == 0 && m < 2);

  short8v ahi[16], alo[16];
  #pragma unroll
  for (int ks = 0; ks < 8; ++ks) {
    short8v h0, l0, h1, l1;
    #pragma unroll
    for (int j = 0; j < 8; ++j) {
      int k = ks * 32 + kq4 * 8 + j;
      u32t hi, lo;
      split_bf(WA[grow * 256 + k], hi, lo);
      h0[j] = (short)hi; l0[j] = (short)lo;
      float vb = bValid ? WB[rowB * 256 + k] : 0.f;
      split_bf(vb, hi, lo);
      h1[j] = (short)hi; l1[j] = (short)lo;
    }
    ahi[ks] = h0;     alo[ks] = l0;
    ahi[8 + ks] = h1; alo[8 + ks] = l1;
  }

  // ---- per-lane epilogue preloads (C: col=lane&15=batch, row=kq4*4+reg=gate) ----
  const int hidC = hidb + kq4;
  float bias4[4], wx[16];
  #pragma unroll
  for (int r = 0; r < 4; ++r) {
    int row = r * 256 + hidC;
    bias4[r] = isL1 ? (bih1[row] + bhh1[row]) : (bih0[row] + bhh0[row]);
    #pragma unroll
    for (int kk = 0; kk < 4; ++kk)
      wx[r * 4 + kk] = isL1 ? 0.f : Wih0[row * 4 + kk];
  }
  float bfc0 = 0.f, bfc1 = 0.f;
  if (wid == 0) { bfc0 = bfc[0]; bfc1 = bfc[1]; }
  const float* yb = y + (group * 16 + m) * T_LEN;

  float cst = 0.f;   // lane-local cell state (c1 on w0-3, c2 on w4-7)

  // exchange map: thread -> (batch row srow, 8 consecutive u32 cols = chunk ch)
  const int srow = tid >> 5;             // 0..15
  const int ch   = tid & 31;             // chunk (16B of bf16-plane / 8 u32 of fp32)
  const int sc8  = ch * 8;               // u32 col base
  const int soff = srow * 512 + ((ch * 16) ^ ((srow & 7) << 4));   // byte, swizzled
  const bool own = (ch >> 1) == slice;   // own slice's cols: direct-LDS path, skip exchange
  // B-frag read map
  const int brow = lane & 15;
  const int bxr  = (brow & 7) << 4;
  const int bco  = kq4 * 16;
  // direct-write byte offset (within plane) for finisher lanes
  const int dwb = m * 512 + ((hidC * 2) ^ ((m & 7) << 4));

#define BRD(sb, pl, ks) \
  (*(const short8v*)((sb) + (pl) * 8192 + brow * 512 + ((((ks) * 64) + bco) ^ bxr)))

  __syncthreads();

  for (int p = 0; p <= T_LEN + 1; ++p) {
    const char* sbR = lds + (p & 1) * 32768;
    char*       sbW = lds + ((p & 1) ^ 1) * 32768;
    const bool act = isL1 ? (p >= 1 && p <= T_LEN) : (p < T_LEN);

    // ---- y prefetch (L0 epilogue input) ----
    float xx[4];
    if (!isL1 && p < T_LEN) {
      #pragma unroll
      for (int kk = 0; kk < 4; ++kk) {
        int ti = p + kk - 3;
        xx[kk] = (ti >= 0) ? yb[ti] : -100.0f;
      }
    }

    // ---- MFMA (3-term split precision) ----
    f32x4 accP = {0.f, 0.f, 0.f, 0.f}, accQ = {0.f, 0.f, 0.f, 0.f};
    if (act) {
      if (!isL1) {
        #pragma unroll
        for (int ks = 0; ks < 8; ++ks) {
          short8v bh = BRD(sbR, 0, ks), bl = BRD(sbR, 1, ks);
          accP = MFMA16(ahi[ks], bh, accP);
          accQ = MFMA16(ahi[ks], bl, accQ);
          accQ = MFMA16(alo[ks], bh, accQ);
        }
      } else {
        #pragma unroll
        for (int ks = 0; ks < 8; ++ks) {
          short8v b1h = BRD(sbR, 0, ks), b1l = BRD(sbR, 1, ks);
          short8v b2h = BRD(sbR, 2, ks), b2l = BRD(sbR, 3, ks);
          accP = MFMA16(ahi[ks], b1h, accP);
          accQ = MFMA16(ahi[ks], b1l, accQ);
          accQ = MFMA16(alo[ks], b1h, accQ);
          accP = MFMA16(ahi[8 + ks], b2h, accP);
          accQ = MFMA16(ahi[8 + ks], b2l, accQ);
          accQ = MFMA16(alo[8 + ks], b2h, accQ);
        }
      }
    }

    // ---- finisher: nonlin + cell update + gen-tagged store + direct LDS write ----
    if (act) {
      float g[4];
      #pragma unroll
      for (int r = 0; r < 4; ++r) g[r] = accP[r] + accQ[r] + bias4[r];
      if (!isL1) {
        #pragma unroll
        for (int kk = 0; kk < 4; ++kk)
          #pragma unroll
          for (int r = 0; r < 4; ++r) g[r] = fmaf(wx[r * 4 + kk], xx[kk], g[r]);
      }
      cst = fsigm(g[1]) * cst + fsigm(g[0]) * ftanh(g[2]);
      float hv = fsigm(g[3]) * ftanh(cst);
      const int step = isL1 ? (p - 1) : p;
      u32t w; __builtin_memcpy(&w, &hv, 4);            // |hv|<1 => bit30 == 0
      w |= ((u32t)((step >> 2) & 1)) << 30;            // embed generation bit
      u32t* dst = (isL1 ? h2b : h1b) + (step & 3) * 32768 + group * 4096 + m * 256 + hidC;
      AST32(dst, w);                                    // fire-and-forget (for remote blocks)
      // own-slice shortcut: write directly into next phase's staging (exact value)
      u32t hi, lo; split_bf(hv, hi, lo);
      char* base = sbW + (isL1 ? 16384 : 0);
      *(unsigned short*)(base + dwb)        = (unsigned short)hi;
      *(unsigned short*)(base + 8192 + dwb) = (unsigned short)lo;
    }

    // ---- issue remote loads for phase p+1 (late: after stores, overlapped w/ FC) ----
    const bool ld1 = !own && (p < T_LEN);                 // h1(p)
    const bool ld2 = !own && (p >= 1 && p <= T_LEN);      // h2(p-1)
    const u64t* s1 = (const u64t*)(h1b + (p & 3) * 32768 + group * 4096 + srow * 256 + sc8);
    const u64t* s2 = (const u64t*)(h2b + ((p - 1) & 3) * 32768 + group * 4096 + srow * 256 + sc8);
    u64t v1[4], v2[4];
    if (ld1) {
      #pragma unroll
      for (int j = 0; j < 4; ++j) v1[j] = ALD64(s1 + j);
    }
    if (ld2) {
      #pragma unroll
      for (int j = 0; j < 4; ++j) v2[j] = ALD64(s2 + j);
    }

    // ---- FC (w0, rotating slice; overlaps the in-flight loads) ----
    if (wid == 0 && p >= 2 && slice == ((p - 2) & 15)) {
      f32x4 aF = {0.f, 0.f, 0.f, 0.f}, aG = {0.f, 0.f, 0.f, 0.f};
      #pragma unroll
      for (int ks = 0; ks < 8; ++ks) {
        short8v b2h = BRD(sbR, 2, ks), b2l = BRD(sbR, 3, ks);
        aF = MFMA16(ahi[8 + ks], b2h, aF);
        aG = MFMA16(ahi[8 + ks], b2l, aG);
        aG = MFMA16(alo[8 + ks], b2h, aG);
      }
      if (lane < 16) {
        float2 o;
        o.x = aF[0] + aG[0] + bfc0;
        o.y = aF[1] + aG[1] + bfc1;
        *(float2*)(&out[(group * 16 + lane) * (T_LEN * 2) + (p - 2) * 2]) = o;
      }
    }

    // ---- check generation bits; re-poll only stale u64s (load RT = natural backoff) ----
    {
      const u32t g1 = (u32t)((p >> 2) & 1);
      const u32t g2 = (u32t)(((p - 1) >> 2) & 1);
      u32t st1 = 0, st2 = 0;
      if (ld1) {
        #pragma unroll
        for (int j = 0; j < 4; ++j)
          if ((((u32t)(v1[j] >> 30)) & 1) != g1 || (((u32t)(v1[j] >> 62)) & 1) != g1)
            st1 |= 1u << j;
      }
      if (ld2) {
        #pragma unroll
        for (int j = 0; j < 4; ++j)
          if ((((u32t)(v2[j] >> 30)) & 1) != g2 || (((u32t)(v2[j] >> 62)) & 1) != g2)
            st2 |= 1u << j;
      }
      int guard = 0;
      while (st1 | st2) {
        #pragma unroll
        for (int j = 0; j < 4; ++j)
          if (st1 & (1u << j)) v1[j] = ALD64(s1 + j);
        #pragma unroll
        for (int j = 0; j < 4; ++j)
          if (st2 & (1u << j)) v2[j] = ALD64(s2 + j);
        u32t n1 = 0, n2 = 0;
        #pragma unroll
        for (int j = 0; j < 4; ++j)
          if ((st1 & (1u << j)) &&
              ((((u32t)(v1[j] >> 30)) & 1) != g1 || (((u32t)(v1[j] >> 62)) & 1) != g1))
            n1 |= 1u << j;
        #pragma unroll
        for (int j = 0; j < 4; ++j)
          if ((st2 & (1u << j)) &&
              ((((u32t)(v2[j] >> 30)) & 1) != g2 || (((u32t)(v2[j] >> 62)) & 1) != g2))
            n2 |= 1u << j;
        st1 = n1; st2 = n2;
        if (st1 | st2) {
          if (++guard > (1 << 16)) { AST32(abortf, 1u); break; }
          if ((guard & 63) == 0 && ALD32(abortf) != 0) break;
          if (guard & 1) __builtin_amdgcn_s_sleep(1);
        }
      }
    }

    // ---- unpack remote words (strip gen bit -> exact fp32 -> split bf16 planes) ----
    if (ld1) {
      short8v vh, vl;
      #pragma unroll
      for (int j = 0; j < 8; ++j) {
        u32t wv = ((u32t)(v1[j >> 1] >> ((j & 1) * 32))) & 0xBFFFFFFFu;
        float f; __builtin_memcpy(&f, &wv, 4);
        u32t hi, lo; split_bf(f, hi, lo);
        vh[j] = (short)hi; vl[j] = (short)lo;
      }
      *(short8v*)(sbW + soff)        = vh;
      *(short8v*)(sbW + 8192 + soff) = vl;
    }
    if (ld2) {
      short8v vh, vl;
      #pragma unroll
      for (int j = 0; j < 8; ++j) {
        u32t wv = ((u32t)(v2[j >> 1] >> ((j & 1) * 32))) & 0xBFFFFFFFu;
        float f; __builtin_memcpy(&f, &wv, 4);
        u32t hi, lo; split_bf(f, hi, lo);
        vh[j] = (short)hi; vl[j] = (short)lo;
      }
      *(short8v*)(sbW + 16384 + soff) = vh;
      *(short8v*)(sbW + 24576 + soff) = vl;
    }

    __syncthreads();   // the ONLY barrier per phase
  }
}

extern "C" void kernel_launch(void* const* d_in, const int* in_sizes, int n_in,
                              void* d_out, int out_size, void* d_ws, size_t ws_size,
                              hipStream_t stream) {
  const float* y    = (const float*)d_in[0];
  const float* Wih0 = (const float*)d_in[1];
  const float* Whh0 = (const float*)d_in[2];
  const float* bih0 = (const float*)d_in[3];
  const float* bhh0 = (const float*)d_in[4];
  const float* Wih1 = (const float*)d_in[5];
  const float* Whh1 = (const float*)d_in[6];
  const float* bih1 = (const float*)d_in[7];
  const float* bhh1 = (const float*)d_in[8];
  const float* Wfc  = (const float*)d_in[9];
  const float* bfc  = (const float*)d_in[10];
  float* out = (float*)d_out;
  u32t*  ws  = (u32t*)d_ws;

  (void)hipFuncSetAttribute(reinterpret_cast<const void*>(lstm_persist),
                            hipFuncAttributeMaxDynamicSharedMemorySize, 131072);

  hipLaunchKernelGGL(init_ws_kernel, dim3(256), dim3(256), 0, stream, ws);
  hipLaunchKernelGGL(lstm_persist, dim3(128), dim3(NTH), 131072, stream,
                     y, Wih0, Whh0, bih0, bhh0, Wih1, Whh1, bih1, bhh1,
                     Wfc, bfc, out, ws);
}